// Round 2
// baseline (2423.113 us; speedup 1.0000x reference)
//
#include <hip/hip_runtime.h>

// VectorQuantizeLayer forward == nearest-code lookup:
//   h = x @ W^T + b                          [16384, 256]
//   idx[m] = argmax_v (2*h.c_v - |c_v|^2)    (== argmin L2; |h|^2 row-const)
//   out[m] = table[idx[m]]                   (straight-through collapses to gather)
// All fp32. R2: 512 thr/block (2 waves/SIMD), LDA_H=258 (conflict-free hs reads),
// NCH=256 single-buffered (half the barriers).

#define M_TOTAL 16384
#define K1 768
#define DQ 256
#define NV 8192

#define RPB 64             // rows per block
#define NCH 256            // codes per chunk
#define NCHUNKS (NV / NCH) // 32
#define KC 32              // K sub-chunk

#define LDA_H 258          // 4-row deltas -> banks +8 apart (1032 mod 32 = 8)
#define LDA_XS 36
#define LDA_WT 258
#define LDA_BS 36

struct SP0 { float xs[RPB][LDA_XS]; float wt[KC][LDA_WT]; };   // 42,240 B
struct SP2 { float bs[NCH][LDA_BS]; };                          // 36,864 B
struct SP3 { int bidx[RPB]; };                                  //    256 B
union SMem { SP0 p0; SP2 p2; SP3 p3; };

__global__ __launch_bounds__(256) void vq_c2_kernel(const float* __restrict__ table,
                                                    float* __restrict__ c2) {
  const int v = blockIdx.x * 256 + threadIdx.x;
  const float4* row = (const float4*)(table + (size_t)v * DQ);
  float s = 0.f;
#pragma unroll 8
  for (int q = 0; q < DQ / 4; ++q) {
    float4 t = row[q];
    s = fmaf(t.x, t.x, s); s = fmaf(t.y, t.y, s);
    s = fmaf(t.z, t.z, s); s = fmaf(t.w, t.w, s);
  }
  c2[v] = s;
}

__global__ __launch_bounds__(512, 2) void vq_main_kernel(
    const float* __restrict__ x, const float* __restrict__ Wm,
    const float* __restrict__ bias, const float* __restrict__ table,
    const float* __restrict__ c2, float* __restrict__ out) {

  __shared__ float hs[RPB][LDA_H];   // 66,048 B
  __shared__ SMem sm;                // 42,240 B   (total 108.3 KB -> 1 block/CU, 8 waves)

  const int tid = threadIdx.x;
  const int tx = tid & 31;    // code group (phase 2) / col group (phase 0)
  const int ty = tid >> 5;    // row group 0..15
  const int rowbase = blockIdx.x * RPB;

  // ---------------- Phase 0: h tile = x @ W^T + b ----------------
  float acc0[4][8];
#pragma unroll
  for (int i = 0; i < 4; ++i)
#pragma unroll
    for (int j = 0; j < 8; ++j) acc0[i][j] = 0.f;

  const int r_ld = tid >> 3;          // 0..63
  const int s_ld = tid & 7;           // 0..7
  const int d_row = tid >> 1;         // 0..255 (W row)
  const int d_k = (tid & 1) * 16;     // 0 or 16

  for (int kc = 0; kc < K1 / KC; ++kc) {
    const int k0 = kc * KC;
    float4 xv = *(const float4*)(x + (size_t)(rowbase + r_ld) * K1 + k0 + s_ld * 4);
    float4 wv[4];
#pragma unroll
    for (int q = 0; q < 4; ++q)
      wv[q] = *(const float4*)(Wm + (size_t)d_row * K1 + k0 + d_k + q * 4);
    __syncthreads();   // prior chunk fully consumed
    *(float4*)&sm.p0.xs[r_ld][s_ld * 4] = xv;
#pragma unroll
    for (int q = 0; q < 4; ++q) {   // transpose W chunk -> k-major
      sm.p0.wt[d_k + q * 4 + 0][d_row] = wv[q].x;
      sm.p0.wt[d_k + q * 4 + 1][d_row] = wv[q].y;
      sm.p0.wt[d_k + q * 4 + 2][d_row] = wv[q].z;
      sm.p0.wt[d_k + q * 4 + 3][d_row] = wv[q].w;
    }
    __syncthreads();
#pragma unroll 2
    for (int k = 0; k < KC; ++k) {
      float a[4];
#pragma unroll
      for (int i = 0; i < 4; ++i) a[i] = sm.p0.xs[ty * 4 + i][k];
#pragma unroll
      for (int j = 0; j < 8; ++j) {
        float w = sm.p0.wt[k][tx + 32 * j];
#pragma unroll
        for (int i = 0; i < 4; ++i) acc0[i][j] = fmaf(a[i], w, acc0[i][j]);
      }
    }
  }
#pragma unroll
  for (int j = 0; j < 8; ++j) {
    float bj = bias[tx + 32 * j];
#pragma unroll
    for (int i = 0; i < 4; ++i)
      hs[ty * 4 + i][tx + 32 * j] = acc0[i][j] + bj;
  }
  __syncthreads();

  // ---------------- Phase 2: score scan + argmax ----------------
  float best[4];
  int bidx[4];
#pragma unroll
  for (int i = 0; i < 4; ++i) { best[i] = -3.4e38f; bidx[i] = 0; }

  const int c_ld = tid >> 1;          // 0..255 code within chunk
  const int ks_ld = (tid & 1) * 16;   // float offset within 32-k slice

  float4 breg[4];
  {
    const float* src = table + (size_t)c_ld * DQ + ks_ld;   // chunk 0: nc=0,kc=0
#pragma unroll
    for (int q = 0; q < 4; ++q) breg[q] = *(const float4*)(src + q * 4);
  }

  float acc[4][8];

  for (int ci = 0; ci < NCHUNKS * 8; ++ci) {   // 256 iters
    const int kc2 = ci & 7;
    const int nc = ci >> 3;
    if (kc2 == 0) {
#pragma unroll
      for (int i = 0; i < 4; ++i)
#pragma unroll
        for (int j = 0; j < 8; ++j) acc[i][j] = 0.f;
    }
    __syncthreads();   // all waves done reading bs (prev iter)
#pragma unroll
    for (int q = 0; q < 4; ++q)
      *(float4*)&sm.p2.bs[c_ld][ks_ld + q * 4] = breg[q];
    if (ci + 1 < NCHUNKS * 8) {   // register prefetch; lands under compute
      const int nc2 = (ci + 1) >> 3, kk = (ci + 1) & 7;
      const float* src = table + (size_t)(nc2 * NCH + c_ld) * DQ + kk * KC + ks_ld;
#pragma unroll
      for (int q = 0; q < 4; ++q) breg[q] = *(const float4*)(src + q * 4);
    }
    __syncthreads();   // bs ready
#pragma unroll
    for (int k4 = 0; k4 < 8; ++k4) {
      float4 a4[4];
      float4 b4[8];
#pragma unroll
      for (int i = 0; i < 4; ++i)
        a4[i] = *(const float4*)&hs[ty * 4 + i][kc2 * KC + k4 * 4];
#pragma unroll
      for (int j = 0; j < 8; ++j)
        b4[j] = *(const float4*)&sm.p2.bs[tx + 32 * j][k4 * 4];
#pragma unroll
      for (int i = 0; i < 4; ++i)
#pragma unroll
        for (int j = 0; j < 8; ++j) {
          acc[i][j] = fmaf(a4[i].x, b4[j].x, acc[i][j]);
          acc[i][j] = fmaf(a4[i].y, b4[j].y, acc[i][j]);
          acc[i][j] = fmaf(a4[i].z, b4[j].z, acc[i][j]);
          acc[i][j] = fmaf(a4[i].w, b4[j].w, acc[i][j]);
        }
    }
    if (kc2 == 7) {   // full K accumulated for this 256-code chunk
#pragma unroll
      for (int j = 0; j < 8; ++j) {
        const int code = nc * NCH + tx + 32 * j;
        const float cc = c2[code];
#pragma unroll
        for (int i = 0; i < 4; ++i) {
          const float s = fmaf(2.f, acc[i][j], -cc);
          if (s > best[i]) { best[i] = s; bidx[i] = code; }   // strict > : first max wins
        }
      }
    }
  }

  // ---------------- argmax reduce across the 32 tx lanes (shuffle butterfly) ----------------
#pragma unroll
  for (int i = 0; i < 4; ++i) {
    float b = best[i];
    int ix = bidx[i];
#pragma unroll
    for (int off = 16; off >= 1; off >>= 1) {   // stays within 32-lane half-wave
      float ob = __shfl_xor(b, off);
      int oi = __shfl_xor(ix, off);
      if (ob > b || (ob == b && oi < ix)) { b = ob; ix = oi; }
    }
    best[i] = b; bidx[i] = ix;
  }
  __syncthreads();   // all waves done reading sm.p2
  if (tx == 0) {
#pragma unroll
    for (int i = 0; i < 4; ++i) sm.p3.bidx[ty * 4 + i] = bidx[i];
  }
  __syncthreads();

  // ---------------- gather: out[row] = table[best] ----------------
  {
    const int row = tid >> 3;        // 0..63
    const int part = tid & 7;        // 0..7
    const int code = sm.p3.bidx[row];
    const float4* src = (const float4*)(table + (size_t)code * DQ + part * 32);
    float4* dst = (float4*)(out + (size_t)(rowbase + row) * DQ + part * 32);
#pragma unroll
    for (int q = 0; q < 8; ++q) dst[q] = src[q];
  }
}

extern "C" void kernel_launch(void* const* d_in, const int* in_sizes, int n_in,
                              void* d_out, int out_size, void* d_ws, size_t ws_size,
                              hipStream_t stream) {
  const float* x     = (const float*)d_in[0];
  const float* Wm    = (const float*)d_in[1];
  const float* bias  = (const float*)d_in[2];
  const float* table = (const float*)d_in[3];
  float* out = (float*)d_out;
  float* c2 = (float*)d_ws;   // 8192 floats = 32 KB scratch

  vq_c2_kernel<<<NV / 256, 256, 0, stream>>>(table, c2);
  vq_main_kernel<<<M_TOTAL / RPB, 512, 0, stream>>>(x, Wm, bias, table, c2, out);
}

// Round 3
// 406.359 us; speedup vs baseline: 5.9630x; 5.9630x over previous
//
#include <hip/hip_runtime.h>

// VQ forward == nearest-code lookup: h = x@W^T + b;  idx = argmax_v(2 h.c_v - |c_v|^2);
// out = table[idx].  R3: bf16-MFMA prefilter (per-row max M) + margin-filtered exact
// fp32 rescore (guarantees argmax == fp32 argmax), h computed via 3-term bf16-split MFMA.

typedef float f32x4 __attribute__((ext_vector_type(4)));
typedef short s16x8 __attribute__((ext_vector_type(8)));
typedef short s16x4 __attribute__((ext_vector_type(4)));

#define M_TOTAL 16384
#define KDIM 768
#define DQ 256
#define NV 8192
#define MARGIN 1.5f

// ws layout (bytes)
#define OFF_TBF   0u            // ushort[NV*DQ]       4,194,304
#define OFF_WH    4194304u      // ushort[DQ*KDIM]       393,216
#define OFF_WL    4587520u      // ushort[DQ*KDIM]       393,216
#define OFF_C2    4980736u      // float[NV]              32,768
#define OFF_M     5013504u      // uint[M_TOTAL]          65,536
#define OFF_BEST  5079040u      // u64[M_TOTAL]          131,072
#define WS_NEEDED 5210112u

static __device__ inline unsigned short bf_rne(float f) {
  unsigned u = __float_as_uint(f);
  u += 0x7FFFu + ((u >> 16) & 1u);
  return (unsigned short)(u >> 16);
}
static __device__ inline unsigned short bf_tr(float f) {
  return (unsigned short)(__float_as_uint(f) >> 16);
}
static __device__ inline float bf_up(unsigned short s) {
  return __uint_as_float(((unsigned)s) << 16);
}
static __device__ inline unsigned mono(float f) {
  unsigned u = __float_as_uint(f);
  return (u & 0x80000000u) ? ~u : (u | 0x80000000u);
}
static __device__ inline float demono(unsigned k) {
  unsigned u = (k & 0x80000000u) ? (k ^ 0x80000000u) : ~k;
  return __uint_as_float(u);
}
static __device__ inline f32x4 mfma16(s16x8 a, s16x8 b, f32x4 c) {
  return __builtin_amdgcn_mfma_f32_16x16x32_bf16(a, b, c, 0, 0, 0);
}

// ============================ prep ============================
#define PB_TBF 1024
#define PB_C2  32
#define PB_W   192
#define PB_INIT 64

__global__ __launch_bounds__(256) void prep_kernel(
    const float* __restrict__ Wm, const float* __restrict__ table,
    unsigned char* __restrict__ ws) {
  unsigned short* tbf = (unsigned short*)(ws + OFF_TBF);
  unsigned short* Wh  = (unsigned short*)(ws + OFF_WH);
  unsigned short* Wl  = (unsigned short*)(ws + OFF_WL);
  float* c2 = (float*)(ws + OFF_C2);
  unsigned* Mu = (unsigned*)(ws + OFF_M);
  unsigned long long* best = (unsigned long long*)(ws + OFF_BEST);
  const int b = blockIdx.x, t = threadIdx.x;
  if (b < PB_TBF) {
    size_t e0 = ((size_t)b * 256 + t) * 8;
    float4 f0 = *(const float4*)(table + e0);
    float4 f1 = *(const float4*)(table + e0 + 4);
    s16x8 v;
    v[0]=(short)bf_rne(f0.x); v[1]=(short)bf_rne(f0.y);
    v[2]=(short)bf_rne(f0.z); v[3]=(short)bf_rne(f0.w);
    v[4]=(short)bf_rne(f1.x); v[5]=(short)bf_rne(f1.y);
    v[6]=(short)bf_rne(f1.z); v[7]=(short)bf_rne(f1.w);
    *(s16x8*)(tbf + e0) = v;
  } else if (b < PB_TBF + PB_C2) {
    const int v = (b - PB_TBF) * 256 + t;
    const float4* row = (const float4*)(table + (size_t)v * DQ);
    float s = 0.f;
    for (int q = 0; q < 64; ++q) {
      float4 x = row[q];
      s = fmaf(x.x, x.x, s); s = fmaf(x.y, x.y, s);
      s = fmaf(x.z, x.z, s); s = fmaf(x.w, x.w, s);
    }
    c2[v] = s;
  } else if (b < PB_TBF + PB_C2 + PB_W) {
    size_t i = ((size_t)(b - PB_TBF - PB_C2) * 256 + t) * 4;
    float4 f = *(const float4*)(Wm + i);
    float fv[4] = {f.x, f.y, f.z, f.w};
    s16x4 vh, vl;
#pragma unroll
    for (int q = 0; q < 4; ++q) {
      unsigned short hi = bf_tr(fv[q]);
      vh[q] = (short)hi;
      vl[q] = (short)bf_rne(fv[q] - bf_up(hi));
    }
    *(s16x4*)(Wh + i) = vh;
    *(s16x4*)(Wl + i) = vl;
  } else {
    const int i = (b - PB_TBF - PB_C2 - PB_W) * 256 + t;
    Mu[i] = 0u;            // mono(-inf-ish): any real score beats 0
    best[i] = 0ull;
  }
}

// ============================ K1: h = x@W^T + b (3-term bf16 split MFMA) ============================
// grid 512 = 128 row-tiles x 4 col-tiles; block 256 (4 waves), tile 128 rows x 64 cols.
__global__ __launch_bounds__(256, 3) void h_gemm_kernel(
    const float* __restrict__ x, const float* __restrict__ bias,
    const unsigned char* __restrict__ ws, float* __restrict__ hout) {
  const unsigned short* Whp = (const unsigned short*)(ws + OFF_WH);
  const unsigned short* Wlp = (const unsigned short*)(ws + OFF_WL);
  __shared__ unsigned short xh[128 * 40], xl[128 * 40];   // rows x padded 32-k chunk
  __shared__ unsigned short wh[64 * 40],  wl[64 * 40];
  const int t = threadIdx.x;
  const int lane = t & 63, wid = t >> 6;
  const int g = lane >> 4, lm = lane & 15;
  const int row_tile = blockIdx.x >> 2, col_tile = blockIdx.x & 3;
  const int r_ld = t >> 1, half = t & 1;       // x staging: 128 rows x 2 halves
  const int n_ld = t >> 2, qtr = t & 3;        // W staging: 64 n x 4 quarters

  f32x4 acc[2][4];
#pragma unroll
  for (int i = 0; i < 2; ++i)
#pragma unroll
    for (int j = 0; j < 4; ++j) acc[i][j] = (f32x4)0.f;

  const float* xsrc = x + (size_t)(row_tile * 128 + r_ld) * KDIM + half * 16;
  const unsigned short* whs = Whp + (size_t)(col_tile * 64 + n_ld) * KDIM + qtr * 8;
  const unsigned short* wls = Wlp + (size_t)(col_tile * 64 + n_ld) * KDIM + qtr * 8;

  float4 px[4]; s16x8 pwh, pwl;
#pragma unroll
  for (int q = 0; q < 4; ++q) px[q] = *(const float4*)(xsrc + q * 4);
  pwh = *(const s16x8*)(whs);
  pwl = *(const s16x8*)(wls);

  for (int kc = 0; kc < KDIM / 32; ++kc) {
    __syncthreads();   // prior chunk fully consumed
    {
      float fv[16] = {px[0].x, px[0].y, px[0].z, px[0].w,
                      px[1].x, px[1].y, px[1].z, px[1].w,
                      px[2].x, px[2].y, px[2].z, px[2].w,
                      px[3].x, px[3].y, px[3].z, px[3].w};
      s16x8 vh0, vh1, vl0, vl1;
#pragma unroll
      for (int e = 0; e < 8; ++e) {
        unsigned short hi = bf_tr(fv[e]);
        vh0[e] = (short)hi; vl0[e] = (short)bf_rne(fv[e] - bf_up(hi));
      }
#pragma unroll
      for (int e = 0; e < 8; ++e) {
        unsigned short hi = bf_tr(fv[8 + e]);
        vh1[e] = (short)hi; vl1[e] = (short)bf_rne(fv[8 + e] - bf_up(hi));
      }
      const int xb = r_ld * 40 + half * 16;
      *(s16x8*)&xh[xb] = vh0; *(s16x8*)&xh[xb + 8] = vh1;
      *(s16x8*)&xl[xb] = vl0; *(s16x8*)&xl[xb + 8] = vl1;
      const int wb = n_ld * 40 + qtr * 8;
      *(s16x8*)&wh[wb] = pwh;
      *(s16x8*)&wl[wb] = pwl;
    }
    if (kc + 1 < KDIM / 32) {   // prefetch next chunk (hidden under MFMA)
      const int k0 = (kc + 1) * 32;
#pragma unroll
      for (int q = 0; q < 4; ++q) px[q] = *(const float4*)(xsrc + k0 + q * 4);
      pwh = *(const s16x8*)(whs + k0);
      pwl = *(const s16x8*)(wls + k0);
    }
    __syncthreads();   // staged chunk ready
    s16x8 ah[2], al[2], bh[4], bl[4];
#pragma unroll
    for (int fr = 0; fr < 2; ++fr) {
      const int rb = (wid * 32 + fr * 16 + lm) * 40 + g * 8;
      ah[fr] = *(const s16x8*)&xh[rb];
      al[fr] = *(const s16x8*)&xl[rb];
    }
#pragma unroll
    for (int fc = 0; fc < 4; ++fc) {
      const int cb = (fc * 16 + lm) * 40 + g * 8;
      bh[fc] = *(const s16x8*)&wh[cb];
      bl[fc] = *(const s16x8*)&wl[cb];
    }
#pragma unroll
    for (int fr = 0; fr < 2; ++fr)
#pragma unroll
      for (int fc = 0; fc < 4; ++fc) {
        acc[fr][fc] = mfma16(ah[fr], bh[fc], acc[fr][fc]);
        acc[fr][fc] = mfma16(ah[fr], bl[fc], acc[fr][fc]);
        acc[fr][fc] = mfma16(al[fr], bh[fc], acc[fr][fc]);
      }
  }
  // epilogue: + bias, store fp32 h
#pragma unroll
  for (int fc = 0; fc < 4; ++fc) {
    const int col_g = col_tile * 64 + fc * 16 + lm;
    const float bv = bias[col_g];
#pragma unroll
    for (int fr = 0; fr < 2; ++fr) {
      const int row_base = row_tile * 128 + wid * 32 + fr * 16 + g * 4;
#pragma unroll
      for (int r = 0; r < 4; ++r)
        hout[(size_t)(row_base + r) * DQ + col_g] = acc[fr][fc][r] + bv;
    }
  }
}

// ============================ K2/K3: score scan ============================
// grid 256 = 64 row-blocks(256 rows) x 4 code-splits(2048 codes); block 512 (8 waves).
// wave = 32 rows, all-K A-frags in regs; 64-code LDS tile, XOR-swizzled.
// MODE 2: per-row bf16-score max -> M.   MODE 3: margin filter + exact fp32 rescore -> best.
template<int MODE>
__global__ __launch_bounds__(512, 2) void scan_kernel(
    const float* __restrict__ h, const float* __restrict__ table,
    unsigned char* __restrict__ ws) {
  const unsigned short* tbf = (const unsigned short*)(ws + OFF_TBF);
  const float* c2 = (const float*)(ws + OFF_C2);
  unsigned* Mu = (unsigned*)(ws + OFF_M);
  unsigned long long* best = (unsigned long long*)(ws + OFF_BEST);
  __shared__ unsigned short bt[64 * 256];   // 32 KB, swizzled: slot ^= (code&7)

  const int t = threadIdx.x, lane = t & 63, wid = t >> 6;
  const int g = lane >> 4, lm = lane & 15;
  const int rb = blockIdx.x >> 2, cs = blockIdx.x & 3;
  const int wrow = rb * 256 + wid * 32;
  const int code0 = cs * 2048;

  // A-frags: wave's 32 rows x K=256, bf16-truncated h, held in regs (64 VGPR)
  s16x8 ah[2][8];
#pragma unroll
  for (int fr = 0; fr < 2; ++fr) {
    const float* hp = h + (size_t)(wrow + fr * 16 + lm) * DQ;
#pragma unroll
    for (int ks = 0; ks < 8; ++ks) {
      float4 a0 = *(const float4*)(hp + ks * 32 + g * 8);
      float4 a1 = *(const float4*)(hp + ks * 32 + g * 8 + 4);
      s16x8 v;
      v[0]=(short)bf_tr(a0.x); v[1]=(short)bf_tr(a0.y);
      v[2]=(short)bf_tr(a0.z); v[3]=(short)bf_tr(a0.w);
      v[4]=(short)bf_tr(a1.x); v[5]=(short)bf_tr(a1.y);
      v[6]=(short)bf_tr(a1.z); v[7]=(short)bf_tr(a1.w);
      ah[fr][ks] = v;
    }
  }

  float rmax[2][4];
  float Mrow[2][4];
#pragma unroll
  for (int fr = 0; fr < 2; ++fr)
#pragma unroll
    for (int r = 0; r < 4; ++r) {
      if (MODE == 2) rmax[fr][r] = -3.4e38f;
      else           Mrow[fr][r] = demono(Mu[wrow + fr * 16 + g * 4 + r]);
    }

  s16x8 pf[4];
#pragma unroll
  for (int p = 0; p < 4; ++p) {
    const int li = p * 512 + t, cl = li >> 5, sl = li & 31;
    pf[p] = *(const s16x8*)(tbf + (size_t)(code0 + cl) * 256 + sl * 8);
  }

  for (int ti = 0; ti < 32; ++ti) {
    __syncthreads();   // all waves done reading bt (prev tile)
#pragma unroll
    for (int p = 0; p < 4; ++p) {
      const int li = p * 512 + t, cl = li >> 5, sl = li & 31;
      *(s16x8*)&bt[cl * 256 + ((sl ^ (cl & 7)) * 8)] = pf[p];
    }
    if (ti + 1 < 32) {
#pragma unroll
      for (int p = 0; p < 4; ++p) {
        const int li = p * 512 + t, cl = li >> 5, sl = li & 31;
        pf[p] = *(const s16x8*)(tbf + (size_t)(code0 + (ti + 1) * 64 + cl) * 256 + sl * 8);
      }
    }
    __syncthreads();   // tile ready

    f32x4 acc[2][4];
#pragma unroll
    for (int fr = 0; fr < 2; ++fr)
#pragma unroll
      for (int fc = 0; fc < 4; ++fc) acc[fr][fc] = (f32x4)0.f;

#pragma unroll
    for (int ks = 0; ks < 8; ++ks)
#pragma unroll
      for (int fc = 0; fc < 4; ++fc) {
        const int cl = fc * 16 + lm, sl = ks * 4 + g;
        s16x8 b = *(const s16x8*)&bt[cl * 256 + ((sl ^ (cl & 7)) * 8)];
        acc[0][fc] = mfma16(ah[0][ks], b, acc[0][fc]);
        acc[1][fc] = mfma16(ah[1][ks], b, acc[1][fc]);
      }

#pragma unroll
    for (int fc = 0; fc < 4; ++fc) {
      const int code_g = code0 + ti * 64 + fc * 16 + lm;
      const float cc = c2[code_g];
#pragma unroll
      for (int fr = 0; fr < 2; ++fr)
#pragma unroll
        for (int r = 0; r < 4; ++r) {
          const float s = fmaf(2.f, acc[fr][fc][r], -cc);
          if (MODE == 2) {
            rmax[fr][r] = fmaxf(rmax[fr][r], s);
          } else {
            if (s >= Mrow[fr][r] - MARGIN) {   // candidate: exact fp32 rescore
              const int row_g = wrow + fr * 16 + g * 4 + r;
              const float4* hp4 = (const float4*)(h + (size_t)row_g * DQ);
              const float4* tp4 = (const float4*)(table + (size_t)code_g * DQ);
              float dot = 0.f;
#pragma unroll 4
              for (int q = 0; q < 64; ++q) {
                float4 a = hp4[q], bb = tp4[q];
                dot = fmaf(a.x, bb.x, dot); dot = fmaf(a.y, bb.y, dot);
                dot = fmaf(a.z, bb.z, dot); dot = fmaf(a.w, bb.w, dot);
              }
              const float sx = fmaf(2.f, dot, -cc);
              const unsigned long long key =
                  ((unsigned long long)mono(sx) << 32) |
                  (unsigned long long)(0xFFFFFFFFu - (unsigned)code_g);
              atomicMax(&best[row_g], key);   // ties -> smaller code wins (np.argmax)
            }
          }
        }
    }
  }

  if (MODE == 2) {
#pragma unroll
    for (int fr = 0; fr < 2; ++fr)
#pragma unroll
      for (int r = 0; r < 4; ++r) {
        float v = rmax[fr][r];
        v = fmaxf(v, __shfl_xor(v, 1));
        v = fmaxf(v, __shfl_xor(v, 2));
        v = fmaxf(v, __shfl_xor(v, 4));
        v = fmaxf(v, __shfl_xor(v, 8));
        if (lm == 0) atomicMax(&Mu[wrow + fr * 16 + g * 4 + r], mono(v));
      }
  }
}

// ============================ K4: gather ============================
__global__ __launch_bounds__(256) void gather_kernel(
    const float* __restrict__ table, const unsigned char* __restrict__ ws,
    float* __restrict__ out) {
  const unsigned long long* best = (const unsigned long long*)(ws + OFF_BEST);
  const int row = blockIdx.x * 64 + (threadIdx.x >> 2);
  const int part = threadIdx.x & 3;
  const unsigned code = 0xFFFFFFFFu - (unsigned)(best[row] & 0xFFFFFFFFull);
  const float4* src = (const float4*)(table + (size_t)code * DQ + part * 64);
  float4* dst = (float4*)(out + (size_t)row * DQ + part * 64);
#pragma unroll
  for (int q = 0; q < 16; ++q) dst[q] = src[q];
}

// ============================ fallback (R1, known-good fp32 path) ============================
#define FB_RPB 64
#define FB_NCH 128
#define FB_LDA_H 260
#define FB_LDA_XS 36
#define FB_LDA_WT 258
#define FB_LDA_BS 36
struct FSP0 { float xs[FB_RPB][FB_LDA_XS]; float wt[32][FB_LDA_WT]; };
struct FSP2 { float bs[2][FB_NCH][FB_LDA_BS]; };
struct FSP3 { float rs[FB_RPB][17]; int ri[FB_RPB][17]; int bidx[FB_RPB]; };
union FSMem { FSP0 p0; FSP2 p2; FSP3 p3; };

__global__ __launch_bounds__(256) void fb_c2_kernel(const float* __restrict__ table,
                                                    float* __restrict__ c2) {
  const int v = blockIdx.x * 256 + threadIdx.x;
  const float4* row = (const float4*)(table + (size_t)v * DQ);
  float s = 0.f;
#pragma unroll 8
  for (int q = 0; q < DQ / 4; ++q) {
    float4 t = row[q];
    s = fmaf(t.x, t.x, s); s = fmaf(t.y, t.y, s);
    s = fmaf(t.z, t.z, s); s = fmaf(t.w, t.w, s);
  }
  c2[v] = s;
}

__global__ __launch_bounds__(256) void fb_main_kernel(
    const float* __restrict__ x, const float* __restrict__ Wm,
    const float* __restrict__ bias, const float* __restrict__ table,
    const float* __restrict__ c2, float* __restrict__ out) {
  __shared__ float hs[FB_RPB][FB_LDA_H];
  __shared__ FSMem sm;
  const int tid = threadIdx.x;
  const int tx = tid & 15, ty = tid >> 4;
  const int rowbase = blockIdx.x * FB_RPB;
  float acc0[4][16];
#pragma unroll
  for (int i = 0; i < 4; ++i)
#pragma unroll
    for (int j = 0; j < 16; ++j) acc0[i][j] = 0.f;
  const int r_ld = tid >> 2, s_ld = tid & 3;
  for (int kc = 0; kc < KDIM / 32; ++kc) {
    const int k0 = kc * 32;
    float4 xa = *(const float4*)(x + (size_t)(rowbase + r_ld) * KDIM + k0 + s_ld * 4);
    float4 xb = *(const float4*)(x + (size_t)(rowbase + r_ld) * KDIM + k0 + (s_ld + 4) * 4);
    float4 wv[8];
#pragma unroll
    for (int q = 0; q < 8; ++q)
      wv[q] = *(const float4*)(Wm + (size_t)tid * KDIM + k0 + q * 4);
    __syncthreads();
    *(float4*)&sm.p0.xs[r_ld][s_ld * 4] = xa;
    *(float4*)&sm.p0.xs[r_ld][(s_ld + 4) * 4] = xb;
#pragma unroll
    for (int q = 0; q < 8; ++q) {
      sm.p0.wt[q * 4 + 0][tid] = wv[q].x;
      sm.p0.wt[q * 4 + 1][tid] = wv[q].y;
      sm.p0.wt[q * 4 + 2][tid] = wv[q].z;
      sm.p0.wt[q * 4 + 3][tid] = wv[q].w;
    }
    __syncthreads();
#pragma unroll 4
    for (int k = 0; k < 32; ++k) {
      float a[4];
#pragma unroll
      for (int i = 0; i < 4; ++i) a[i] = sm.p0.xs[ty * 4 + i][k];
#pragma unroll
      for (int j = 0; j < 16; ++j) {
        float w = sm.p0.wt[k][tx + 16 * j];
#pragma unroll
        for (int i = 0; i < 4; ++i) acc0[i][j] = fmaf(a[i], w, acc0[i][j]);
      }
    }
  }
#pragma unroll
  for (int j = 0; j < 16; ++j) {
    float bj = bias[tx + 16 * j];
#pragma unroll
    for (int i = 0; i < 4; ++i)
      hs[ty * 4 + i][tx + 16 * j] = acc0[i][j] + bj;
  }
  __syncthreads();
  float bestv[4]; int bidx[4];
#pragma unroll
  for (int i = 0; i < 4; ++i) { bestv[i] = -3.4e38f; bidx[i] = 0; }
  const int c_ld = tid >> 1, ks_ld = (tid & 1) * 16;
  float4 breg[4];
  {
    const float* src = table + (size_t)c_ld * DQ + ks_ld;
#pragma unroll
    for (int q = 0; q < 4; ++q) breg[q] = *(const float4*)(src + q * 4);
  }
  float acc[4][8];
  for (int ci = 0; ci < 512; ++ci) {
    const int cur = ci & 1, kc = ci & 7, nc = ci >> 3;
    if (kc == 0) {
#pragma unroll
      for (int i = 0; i < 4; ++i)
#pragma unroll
        for (int j = 0; j < 8; ++j) acc[i][j] = 0.f;
    }
    __syncthreads();
#pragma unroll
    for (int q = 0; q < 4; ++q)
      *(float4*)&sm.p2.bs[cur][c_ld][ks_ld + q * 4] = breg[q];
    if (ci + 1 < 512) {
      const int nc2 = (ci + 1) >> 3, kk = (ci + 1) & 7;
      const float* src = table + (size_t)(nc2 * FB_NCH + c_ld) * DQ + kk * 32 + ks_ld;
#pragma unroll
      for (int q = 0; q < 4; ++q) breg[q] = *(const float4*)(src + q * 4);
    }
    __syncthreads();
#pragma unroll
    for (int k4 = 0; k4 < 8; ++k4) {
      float4 a4[4]; float4 b4[8];
#pragma unroll
      for (int i = 0; i < 4; ++i)
        a4[i] = *(const float4*)&hs[ty * 4 + i][kc * 32 + k4 * 4];
#pragma unroll
      for (int j = 0; j < 8; ++j)
        b4[j] = *(const float4*)&sm.p2.bs[cur][tx + 16 * j][k4 * 4];
#pragma unroll
      for (int i = 0; i < 4; ++i)
#pragma unroll
        for (int j = 0; j < 8; ++j) {
          acc[i][j] = fmaf(a4[i].x, b4[j].x, acc[i][j]);
          acc[i][j] = fmaf(a4[i].y, b4[j].y, acc[i][j]);
          acc[i][j] = fmaf(a4[i].z, b4[j].z, acc[i][j]);
          acc[i][j] = fmaf(a4[i].w, b4[j].w, acc[i][j]);
        }
    }
    if (kc == 7) {
#pragma unroll
      for (int j = 0; j < 8; ++j) {
        const int code = nc * FB_NCH + tx + 16 * j;
        const float cc = c2[code];
#pragma unroll
        for (int i = 0; i < 4; ++i) {
          const float s = fmaf(2.f, acc[i][j], -cc);
          if (s > bestv[i]) { bestv[i] = s; bidx[i] = code; }
        }
      }
    }
  }
  __syncthreads();
#pragma unroll
  for (int i = 0; i < 4; ++i) {
    sm.p3.rs[ty * 4 + i][tx] = bestv[i];
    sm.p3.ri[ty * 4 + i][tx] = bidx[i];
  }
  __syncthreads();
  if (tid < FB_RPB) {
    float bsc = sm.p3.rs[tid][0]; int bix = sm.p3.ri[tid][0];
    for (int tt = 1; tt < 16; ++tt) {
      float s = sm.p3.rs[tid][tt]; int ix = sm.p3.ri[tid][tt];
      if (s > bsc || (s == bsc && ix < bix)) { bsc = s; bix = ix; }
    }
    sm.p3.bidx[tid] = bix;
  }
  __syncthreads();
  {
    const int row = tid >> 2, part = tid & 3;
    const int code = sm.p3.bidx[row];
    const float4* src = (const float4*)(table + (size_t)code * DQ + part * 64);
    float4* dst = (float4*)(out + (size_t)(rowbase + row) * DQ + part * 64);
#pragma unroll
    for (int q = 0; q < 16; ++q) dst[q] = src[q];
  }
}

// ============================ launch ============================
extern "C" void kernel_launch(void* const* d_in, const int* in_sizes, int n_in,
                              void* d_out, int out_size, void* d_ws, size_t ws_size,
                              hipStream_t stream) {
  const float* x     = (const float*)d_in[0];
  const float* Wm    = (const float*)d_in[1];
  const float* bias  = (const float*)d_in[2];
  const float* table = (const float*)d_in[3];
  float* out = (float*)d_out;

  if (ws_size < WS_NEEDED) {   // fallback: known-good fp32 path
    float* c2 = (float*)d_ws;
    fb_c2_kernel<<<NV / 256, 256, 0, stream>>>(table, c2);
    fb_main_kernel<<<M_TOTAL / FB_RPB, 256, 0, stream>>>(x, Wm, bias, table, c2, out);
    return;
  }

  unsigned char* ws = (unsigned char*)d_ws;
  prep_kernel<<<PB_TBF + PB_C2 + PB_W + PB_INIT, 256, 0, stream>>>(Wm, table, ws);
  h_gemm_kernel<<<512, 256, 0, stream>>>(x, bias, ws, out);   // h lives in d_out
  scan_kernel<2><<<256, 512, 0, stream>>>(out, table, ws);    // per-row bf16 max -> M
  scan_kernel<3><<<256, 512, 0, stream>>>(out, table, ws);    // margin filter + exact rescore
  gather_kernel<<<M_TOTAL / 64, 256, 0, stream>>>(table, ws, out);
}